// Round 1
// baseline (11709.555 us; speedup 1.0000x reference)
//
#include <hip/hip_runtime.h>
#include <math.h>

#define BTOT 16384
#define MM 8   // batch elements per block

// ws offsets (floats)
#define OFF_WIHT 0
#define OFF_WHHT 32768
#define OFF_WQT  98304
#define OFF_WVT  114688
#define OFF_OUTT 131072
#define OFF_W1T  147456
#define OFF_W2T  180224
#define PREP_TOTAL 184832

__device__ __forceinline__ float sigm(float v) { return 1.0f / (1.0f + expf(-v)); }

__global__ void prep_kernel(const float* __restrict__ W_ih,
                            const float* __restrict__ W_hh,
                            const float* __restrict__ in_proj_w,
                            const float* __restrict__ out_proj_w,
                            const float* __restrict__ traj_W1,
                            const float* __restrict__ traj_W2,
                            float* __restrict__ ws) {
    int idx = blockIdx.x * 256 + threadIdx.x;
    if (idx < 32768) { int k = idx >> 9, j = idx & 511; ws[OFF_WIHT + idx] = W_ih[j * 64 + k]; return; }
    idx -= 32768;
    if (idx < 65536) { int k = idx >> 9, j = idx & 511; ws[OFF_WHHT + idx] = W_hh[j * 128 + k]; return; }
    idx -= 65536;
    if (idx < 16384) { int k = idx >> 7, d = idx & 127; ws[OFF_WQT + idx] = in_proj_w[d * 128 + k]; return; }
    idx -= 16384;
    if (idx < 16384) { int j = idx >> 7, d = idx & 127; ws[OFF_WVT + idx] = in_proj_w[(256 + d) * 128 + j]; return; }
    idx -= 16384;
    if (idx < 16384) { int k = idx >> 7, d = idx & 127; ws[OFF_OUTT + idx] = out_proj_w[d * 128 + k]; return; }
    idx -= 16384;
    if (idx < 32768) { int k = idx >> 7, j = idx & 127; ws[OFF_W1T + idx] = traj_W1[j * 256 + k]; return; }
    idx -= 32768;
    if (idx < 4608)  { int j = idx / 36, r = idx - j * 36; ws[OFF_W2T + idx] = traj_W2[r * 128 + j]; return; }
}

__global__ __launch_bounds__(256, 2)
void traj_kernel(const float* __restrict__ x, const float* __restrict__ neighbors,
                 const int* __restrict__ ncnt,
                 const float* __restrict__ embed_W, const float* __restrict__ embed_b,
                 const float* __restrict__ b_ih, const float* __restrict__ b_hh,
                 const float* __restrict__ in_proj_w, const float* __restrict__ in_proj_b,
                 const float* __restrict__ out_proj_b,
                 const float* __restrict__ traj_b1, const float* __restrict__ traj_b2,
                 const float* __restrict__ prob_W, const float* __restrict__ prob_b,
                 const float* __restrict__ ws,
                 float* __restrict__ out) {
    __shared__ float xs[224];          // x for 8 elements (8*4*7)
    __shared__ float embbuf[2048];     // target emb (8*4*64) OR neighbor emb (32*64)
    __shared__ float hbuf[1024];       // h state for 8 elements (8*128), becomes h_t
    __shared__ float nbuf[224];        // one element's neighbors (32*7)
    __shared__ float h_n[32 * 129];    // neighbor hidden, padded stride vs bank conflicts
    __shared__ float q_lds[128];
    __shared__ float qW[512];          // 4 heads x 128
    __shared__ float scb[128];         // scores 4x32
    __shared__ float wb[128];          // softmax weights (unnormalized, then scaled at use)
    __shared__ float hwb[512];         // 4 heads x 128: sum_n w*h_n
    __shared__ float apb[128];         // attn pre-out_proj
    __shared__ float socb[128];        // h_social
    __shared__ float hidb[128];
    __shared__ float red[4];
    __shared__ float logits[3];

    const int tid = threadIdx.x;
    const int base = blockIdx.x * MM;
    const int d = tid & 127;
    const int mh = tid >> 7;  // 0/1

    const float* WihT = ws + OFF_WIHT;  // [64][512]
    const float* WhhT = ws + OFF_WHHT;  // [128][512]
    const float* WqT  = ws + OFF_WQT;   // [128][128]
    const float* WvT  = ws + OFF_WVT;   // [128][128]
    const float* OutT = ws + OFF_OUTT;  // [128][128]
    const float* W1T  = ws + OFF_W1T;   // [256][128]
    const float* W2T  = ws + OFF_W2T;   // [128][36]

    // ---------------- target encoder ----------------
    if (tid < 224) xs[tid] = x[base * 28 + tid];
    #pragma unroll
    for (int r = 0; r < 4; ++r) hbuf[tid + 256 * r] = 0.0f;
    __syncthreads();

    #pragma unroll
    for (int r = 0; r < 8; ++r) {
        int idx = tid + r * 256;
        int e = idx & 63, t = (idx >> 6) & 3, m = idx >> 8;
        float a = embed_b[e];
        #pragma unroll
        for (int f = 0; f < 7; ++f) a = fmaf(xs[m * 28 + t * 7 + f], embed_W[e * 7 + f], a);
        embbuf[idx] = fmaxf(a, 0.0f);
    }

    const float bi  = b_ih[d]       + b_hh[d];
    const float bfg = b_ih[128 + d] + b_hh[128 + d];
    const float bg  = b_ih[256 + d] + b_hh[256 + d];
    const float bo  = b_ih[384 + d] + b_hh[384 + d];
    float creg[4] = {0.f, 0.f, 0.f, 0.f};
    __syncthreads();

    for (int t = 0; t < 4; ++t) {
        float ai[4], af[4], ag[4], ao[4];
        #pragma unroll
        for (int q = 0; q < 4; ++q) { ai[q] = bi; af[q] = bfg; ag[q] = bg; ao[q] = bo; }
        for (int k = 0; k < 64; ++k) {
            const float* wrow = WihT + k * 512 + d;
            float wi = wrow[0], wf = wrow[128], wg = wrow[256], wo = wrow[384];
            #pragma unroll
            for (int q = 0; q < 4; ++q) {
                float v = embbuf[(mh * 4 + q) * 256 + t * 64 + k];
                ai[q] = fmaf(wi, v, ai[q]); af[q] = fmaf(wf, v, af[q]);
                ag[q] = fmaf(wg, v, ag[q]); ao[q] = fmaf(wo, v, ao[q]);
            }
        }
        for (int k = 0; k < 128; ++k) {
            const float* wrow = WhhT + k * 512 + d;
            float wi = wrow[0], wf = wrow[128], wg = wrow[256], wo = wrow[384];
            #pragma unroll
            for (int q = 0; q < 4; ++q) {
                float v = hbuf[(mh * 4 + q) * 128 + k];
                ai[q] = fmaf(wi, v, ai[q]); af[q] = fmaf(wf, v, af[q]);
                ag[q] = fmaf(wg, v, ag[q]); ao[q] = fmaf(wo, v, ao[q]);
            }
        }
        __syncthreads();  // everyone done reading hbuf
        #pragma unroll
        for (int q = 0; q < 4; ++q) {
            float ig = sigm(ai[q]);
            float fg = sigm(af[q]);
            float gg = tanhf(ag[q]);
            float og = sigm(ao[q]);
            creg[q] = fg * creg[q] + ig * gg;
            hbuf[(mh * 4 + q) * 128 + d] = og * tanhf(creg[q]);
        }
        __syncthreads();
    }

    // ---------------- per-element neighbor encoder + attention + heads ----------------
    const float scl = 0.17677669529663687f;  // 1/sqrt(32)
    for (int m = 0; m < MM; ++m) {
        const int b = base + m;
        const int cnt = ncnt[b];

        if (tid < 224) nbuf[tid] = neighbors[b * 224 + tid];
        __syncthreads();

        #pragma unroll
        for (int r = 0; r < 8; ++r) {
            int idx = tid + r * 256;
            int e = idx & 63, n = idx >> 6;
            float a = embed_b[e];
            #pragma unroll
            for (int f = 0; f < 7; ++f) a = fmaf(nbuf[n * 7 + f], embed_W[e * 7 + f], a);
            embbuf[idx] = fmaxf(a, 0.0f);
        }
        __syncthreads();

        // neighbor LSTM step from zero state: only i, g, o gates needed
        {
            const int nh = tid >> 7;
            float aI[16], aG[16], aO[16];
            #pragma unroll
            for (int n2 = 0; n2 < 16; ++n2) { aI[n2] = bi; aG[n2] = bg; aO[n2] = bo; }
            for (int k = 0; k < 64; ++k) {
                const float* wrow = WihT + k * 512 + d;
                float wi = wrow[0], wg = wrow[256], wo = wrow[384];
                #pragma unroll
                for (int n2 = 0; n2 < 16; ++n2) {
                    float v = embbuf[(nh * 16 + n2) * 64 + k];
                    aI[n2] = fmaf(wi, v, aI[n2]);
                    aG[n2] = fmaf(wg, v, aG[n2]);
                    aO[n2] = fmaf(wo, v, aO[n2]);
                }
            }
            #pragma unroll
            for (int n2 = 0; n2 < 16; ++n2) {
                float ig = sigm(aI[n2]);
                float gg = tanhf(aG[n2]);
                float og = sigm(aO[n2]);
                h_n[(nh * 16 + n2) * 129 + d] = og * tanhf(ig * gg);
            }
        }
        // q = h_t @ Wq.T + bq (overlaps with nothing hazardous; synced below)
        if (tid < 128) {
            float a0 = 0.f, a1 = 0.f;
            for (int k = 0; k < 128; k += 2) {
                a0 = fmaf(hbuf[m * 128 + k],     WqT[k * 128 + tid],       a0);
                a1 = fmaf(hbuf[m * 128 + k + 1], WqT[(k + 1) * 128 + tid], a1);
            }
            q_lds[tid] = in_proj_b[tid] + a0 + a1;
        }
        __syncthreads();

        // qkb[h] = q . bk ; qW[h][j] = sum_d q[h,d] * Wk[h*32+d, j]
        if (tid < 4) {
            float a = 0.f;
            for (int dd = 0; dd < 32; ++dd) a = fmaf(q_lds[tid * 32 + dd], in_proj_b[128 + tid * 32 + dd], a);
            red[tid] = a;
        }
        {
            int j = tid & 127;
            int hb = tid >> 7;
            #pragma unroll
            for (int hh = 0; hh < 2; ++hh) {
                int hc = hb + hh * 2;
                float a = 0.f;
                for (int dd = 0; dd < 32; ++dd)
                    a = fmaf(q_lds[hc * 32 + dd], in_proj_w[(128 + hc * 32 + dd) * 128 + j], a);
                qW[hc * 128 + j] = a;
            }
        }
        __syncthreads();

        // scores[h][n]
        if (tid < 128) {
            int hc = tid >> 5, n = tid & 31;
            float a0 = 0.f, a1 = 0.f;
            for (int j = 0; j < 128; j += 2) {
                a0 = fmaf(qW[hc * 128 + j],     h_n[n * 129 + j],     a0);
                a1 = fmaf(qW[hc * 128 + j + 1], h_n[n * 129 + j + 1], a1);
            }
            float a = (a0 + a1 + red[hc]) * scl;
            scb[tid] = (n < cnt) ? a : -1e9f;
        }
        __syncthreads();

        if (tid < 4) {
            float mx = scb[tid * 32];
            for (int n = 1; n < 32; ++n) mx = fmaxf(mx, scb[tid * 32 + n]);
            red[tid] = mx;
        }
        __syncthreads();
        if (tid < 128) wb[tid] = expf(scb[tid] - red[tid >> 5]);
        __syncthreads();
        if (tid < 4) {
            float s = 0.f;
            for (int n = 0; n < 32; ++n) s += wb[tid * 32 + n];
            red[tid] = 1.0f / s;
        }
        __syncthreads();

        // attn_weights output (head-mean * mask)
        if (tid < 32) {
            float aw = 0.25f * (wb[tid] * red[0] + wb[32 + tid] * red[1] +
                                wb[64 + tid] * red[2] + wb[96 + tid] * red[3]);
            out[BTOT * 39 + b * 32 + tid] = (tid < cnt) ? aw : 0.0f;
        }
        // hw[h][j] = sum_n w[h,n] * h_n[n,j]
        {
            int j = tid & 127;
            int hb = tid >> 7;
            #pragma unroll
            for (int hh = 0; hh < 2; ++hh) {
                int hc = hb + hh * 2;
                float a = 0.f;
                for (int n = 0; n < 32; ++n) a = fmaf(wb[hc * 32 + n], h_n[n * 129 + j], a);
                hwb[hc * 128 + j] = a * red[hc];
            }
        }
        __syncthreads();

        // attn pre-projection: ap[hd] = bv[hd] + sum_j Wv[hd,j]*hw[h,j]
        if (tid < 128) {
            int hc = tid >> 5;
            float a0 = 0.f, a1 = 0.f;
            for (int j = 0; j < 128; j += 2) {
                a0 = fmaf(WvT[j * 128 + tid],       hwb[hc * 128 + j],     a0);
                a1 = fmaf(WvT[(j + 1) * 128 + tid], hwb[hc * 128 + j + 1], a1);
            }
            apb[tid] = in_proj_b[256 + tid] + a0 + a1;
        }
        __syncthreads();

        // out_proj + has_nb mask
        if (tid < 128) {
            float a0 = 0.f, a1 = 0.f;
            for (int k = 0; k < 128; k += 2) {
                a0 = fmaf(apb[k],     OutT[k * 128 + tid],       a0);
                a1 = fmaf(apb[k + 1], OutT[(k + 1) * 128 + tid], a1);
            }
            float s = out_proj_b[tid] + a0 + a1;
            socb[tid] = (cnt > 0) ? s : 0.0f;
        }
        __syncthreads();

        // hid = relu(W1 @ [h_t, h_social] + b1) ; logits on spare threads
        if (tid < 128) {
            float a0 = 0.f, a1 = 0.f;
            for (int k = 0; k < 128; k += 2) {
                a0 = fmaf(hbuf[m * 128 + k],     W1T[k * 128 + tid],       a0);
                a1 = fmaf(hbuf[m * 128 + k + 1], W1T[(k + 1) * 128 + tid], a1);
            }
            for (int k = 0; k < 128; k += 2) {
                a0 = fmaf(socb[k],     W1T[(128 + k) * 128 + tid], a0);
                a1 = fmaf(socb[k + 1], W1T[(129 + k) * 128 + tid], a1);
            }
            hidb[tid] = fmaxf(traj_b1[tid] + a0 + a1, 0.0f);
        } else if (tid < 131) {
            int r = tid - 128;
            float a = prob_b[r];
            for (int k = 0; k < 128; ++k) a = fmaf(hbuf[m * 128 + k], prob_W[r * 256 + k], a);
            for (int k = 0; k < 128; ++k) a = fmaf(socb[k], prob_W[r * 256 + 128 + k], a);
            logits[r] = a;
        }
        __syncthreads();

        // traj output + probs
        if (tid < 36) {
            float a = traj_b2[tid];
            for (int j = 0; j < 128; ++j) a = fmaf(hidb[j], W2T[j * 36 + tid], a);
            out[b * 36 + tid] = a;
        } else if (tid == 64) {
            float l0 = logits[0], l1 = logits[1], l2 = logits[2];
            float mx = fmaxf(l0, fmaxf(l1, l2));
            float e0 = expf(l0 - mx), e1 = expf(l1 - mx), e2 = expf(l2 - mx);
            float inv = 1.0f / (e0 + e1 + e2);
            out[BTOT * 36 + b * 3 + 0] = e0 * inv;
            out[BTOT * 36 + b * 3 + 1] = e1 * inv;
            out[BTOT * 36 + b * 3 + 2] = e2 * inv;
        }
        __syncthreads();
    }
}

extern "C" void kernel_launch(void* const* d_in, const int* in_sizes, int n_in,
                              void* d_out, int out_size, void* d_ws, size_t ws_size,
                              hipStream_t stream) {
    (void)in_sizes; (void)n_in; (void)out_size; (void)ws_size;
    const float* x         = (const float*)d_in[0];
    const float* neighbors = (const float*)d_in[1];
    const int*   ncnt      = (const int*)d_in[2];
    const float* embed_W   = (const float*)d_in[3];
    const float* embed_b   = (const float*)d_in[4];
    const float* W_ih      = (const float*)d_in[5];
    const float* W_hh      = (const float*)d_in[6];
    const float* b_ih      = (const float*)d_in[7];
    const float* b_hh      = (const float*)d_in[8];
    const float* in_proj_w = (const float*)d_in[9];
    const float* in_proj_b = (const float*)d_in[10];
    const float* out_proj_w= (const float*)d_in[11];
    const float* out_proj_b= (const float*)d_in[12];
    const float* traj_W1   = (const float*)d_in[13];
    const float* traj_b1   = (const float*)d_in[14];
    const float* traj_W2   = (const float*)d_in[15];
    const float* traj_b2   = (const float*)d_in[16];
    const float* prob_W    = (const float*)d_in[17];
    const float* prob_b    = (const float*)d_in[18];
    float* ws  = (float*)d_ws;
    float* out = (float*)d_out;

    hipLaunchKernelGGL(prep_kernel, dim3(PREP_TOTAL / 256), dim3(256), 0, stream,
                       W_ih, W_hh, in_proj_w, out_proj_w, traj_W1, traj_W2, ws);
    hipLaunchKernelGGL(traj_kernel, dim3(BTOT / MM), dim3(256), 0, stream,
                       x, neighbors, ncnt, embed_W, embed_b, b_ih, b_hh,
                       in_proj_w, in_proj_b, out_proj_b, traj_b1, traj_b2,
                       prob_W, prob_b, ws, out);
}